// Round 6
// baseline (130.186 us; speedup 1.0000x reference)
//
#include <hip/hip_runtime.h>
#include <hip/hip_bf16.h>

// SequenceReductionAttention (PVT-style SRA).
// B=4, N=4096 (64x64), C=256, heads=8, d=32, SR=2 -> N'=1024 (32x32).
//
// Round 6: latency attack on attention.
//  - kv GEMM writes K row-major [4096][256] and V TRANSPOSED vt[b,h][d][kv]
//  - attn: no LDS in main loop (K,V^T straight from global, L2-resident),
//    split-KV x2: 2 waves per 32-q block each do half of KV (8 tiles),
//    merged via LDS at the end (flat softmax -> plain add).
//  - grid 4096 blocks x 2 waves = 8192 waves = 32/CU (was 16/CU).

typedef __attribute__((ext_vector_type(8))) short bf16x8;
typedef __attribute__((ext_vector_type(8))) unsigned short u16x8;
typedef __attribute__((ext_vector_type(4))) float f32x4;
typedef __attribute__((ext_vector_type(16))) float f32x16;
typedef __attribute__((ext_vector_type(2))) unsigned u32x2v;
typedef __attribute__((ext_vector_type(4))) unsigned u32x4v;

__device__ inline unsigned short f2bf(float f) {
  unsigned u = __float_as_uint(f);
  u += 0x7fffu + ((u >> 16) & 1u);
  return (unsigned short)(u >> 16);
}

// ---------------------------------------------------------------------------
// fp32 -> bf16 cast, 8 elems/thread.
__global__ __launch_bounds__(256) void cast_bf16(
    const float* __restrict__ in, unsigned short* __restrict__ out, int n8) {
  int i = blockIdx.x * 256 + threadIdx.x;
  if (i >= n8) return;
  float4 a = reinterpret_cast<const float4*>(in)[i * 2];
  float4 b = reinterpret_cast<const float4*>(in)[i * 2 + 1];
  ushort4 lo, hi;
  lo.x = f2bf(a.x); lo.y = f2bf(a.y); lo.z = f2bf(a.z); lo.w = f2bf(a.w);
  hi.x = f2bf(b.x); hi.y = f2bf(b.y); hi.z = f2bf(b.z); hi.w = f2bf(b.w);
  reinterpret_cast<ushort4*>(out)[i * 2] = lo;
  reinterpret_cast<ushort4*>(out)[i * 2 + 1] = hi;
}

// ---------------------------------------------------------------------------
// sr_w [256 o][256 ci][4 tap] fp32 -> srw_bf [256 o][4 tap][256 ci] bf16.
__global__ __launch_bounds__(256) void perm_srw(
    const float* __restrict__ w, unsigned short* __restrict__ wp) {
  int o = blockIdx.x, t = threadIdx.x;
  float4 v = reinterpret_cast<const float4*>(w + (size_t)o * 1024)[t];
  wp[(size_t)o * 1024 + 0 * 256 + t] = f2bf(v.x);
  wp[(size_t)o * 1024 + 1 * 256 + t] = f2bf(v.y);
  wp[(size_t)o * 1024 + 2 * 256 + t] = f2bf(v.z);
  wp[(size_t)o * 1024 + 3 * 256 + t] = f2bf(v.w);
}

// ---------------------------------------------------------------------------
// MFMA GEMM: C = (A[M,K](bf16) @ W[N,K](f32->bf16)^T) * oscale (+bias).
// Block 128x64, BK=32, 4 waves. KV_MODE: cols<256 -> K row-major ld256;
// cols>=256 -> V transposed vt[(b*8+head)*32+d][1024 kv].
template <bool BF16_OUT, bool HAS_BIAS, bool KV_MODE>
__global__ __launch_bounds__(256) void mfma_gemm(
    const unsigned short* __restrict__ A, const float* __restrict__ W,
    const float* __restrict__ bias, void* __restrict__ Cv,
    void* __restrict__ Vtp, int M, int N, int K, float oscale) {
  __shared__ unsigned short Asb[128 * 40];
  __shared__ unsigned short Bsb[64 * 40];
  const int tid = threadIdx.x;
  const int w = tid >> 6, l = tid & 63, c = l & 15, g = l >> 4;
  const int wr = w >> 1, wc = w & 1;
  const int m0 = blockIdx.y * 128, n0 = blockIdx.x * 64;
  const int ar = tid >> 1, ah = tid & 1;
  const int bn = tid >> 2, bq = tid & 3;

  f32x4 acc[4][2];
#pragma unroll
  for (int mt = 0; mt < 4; ++mt)
#pragma unroll
    for (int nt = 0; nt < 2; ++nt)
#pragma unroll
      for (int r = 0; r < 4; ++r) acc[mt][nt][r] = 0.f;

  for (int k0 = 0; k0 < K; k0 += 32) {
    __syncthreads();
    {
      const unsigned short* asrc = A + (size_t)(m0 + ar) * K + k0 + ah * 16;
      u16x8 a0 = *reinterpret_cast<const u16x8*>(asrc);
      u16x8 a1 = *reinterpret_cast<const u16x8*>(asrc + 8);
      *reinterpret_cast<u16x8*>(&Asb[ar * 40 + ah * 16]) = a0;
      *reinterpret_cast<u16x8*>(&Asb[ar * 40 + ah * 16 + 8]) = a1;
    }
    {
      const float* wsrc = W + (size_t)(n0 + bn) * K + k0 + bq * 8;
      float4 w0 = *reinterpret_cast<const float4*>(wsrc);
      float4 w1 = *reinterpret_cast<const float4*>(wsrc + 4);
      u16x8 wb;
      wb[0] = f2bf(w0.x); wb[1] = f2bf(w0.y); wb[2] = f2bf(w0.z); wb[3] = f2bf(w0.w);
      wb[4] = f2bf(w1.x); wb[5] = f2bf(w1.y); wb[6] = f2bf(w1.z); wb[7] = f2bf(w1.w);
      *reinterpret_cast<u16x8*>(&Bsb[bn * 40 + bq * 8]) = wb;
    }
    __syncthreads();
    bf16x8 af[4], bfr[2];
#pragma unroll
    for (int mt = 0; mt < 4; ++mt)
      af[mt] = *reinterpret_cast<const bf16x8*>(
          &Asb[(wr * 64 + mt * 16 + c) * 40 + g * 8]);
#pragma unroll
    for (int nt = 0; nt < 2; ++nt)
      bfr[nt] = *reinterpret_cast<const bf16x8*>(
          &Bsb[(wc * 32 + nt * 16 + c) * 40 + g * 8]);
#pragma unroll
    for (int mt = 0; mt < 4; ++mt)
#pragma unroll
      for (int nt = 0; nt < 2; ++nt)
        acc[mt][nt] = __builtin_amdgcn_mfma_f32_16x16x32_bf16(
            af[mt], bfr[nt], acc[mt][nt], 0, 0, 0);
  }

#pragma unroll
  for (int mt = 0; mt < 4; ++mt)
#pragma unroll
    for (int nt = 0; nt < 2; ++nt) {
      int row = m0 + wr * 64 + mt * 16 + g * 4;
      int col = n0 + wc * 32 + nt * 16 + c;
      float bv = HAS_BIAS ? bias[col] : 0.f;
#pragma unroll
      for (int r = 0; r < 4; ++r) {
        float v = acc[mt][nt][r] * oscale + bv;
        if (KV_MODE) {
          if (col < 256) {
            ((unsigned short*)Cv)[(size_t)(row + r) * 256 + col] = f2bf(v);
          } else {
            int head = (col - 256) >> 5, d = (col - 256) & 31;
            int rr = row + r;
            ((unsigned short*)Vtp)[
                ((size_t)(((rr >> 10) << 3) + head) * 32 + d) * 1024 +
                (rr & 1023)] = f2bf(v);
          }
        } else if (BF16_OUT) {
          ((unsigned short*)Cv)[(size_t)(row + r) * N + col] = f2bf(v);
        } else {
          ((float*)Cv)[(size_t)(row + r) * N + col] = v;
        }
      }
    }
}

// ---------------------------------------------------------------------------
// Conv(k=2,s=2) as MFMA GEMM with tap-major K. Block 64x64, 4 waves (32x32).
__global__ __launch_bounds__(256) void conv_mfma(
    const unsigned short* __restrict__ Xb, const unsigned short* __restrict__ Wp,
    const float* __restrict__ bias, float* __restrict__ C) {
  __shared__ unsigned short Asb[64 * 40];
  __shared__ unsigned short Bsb[64 * 40];
  const int tid = threadIdx.x;
  const int w = tid >> 6, l = tid & 63, c = l & 15, g = l >> 4;
  const int wr = w >> 1, wc = w & 1;
  const int m0 = blockIdx.y * 64, n0 = blockIdx.x * 64;
  const int sr = tid >> 2, sh = tid & 3;

  int base[4];
  {
    int row = m0 + sr;
    int b = row >> 10, o = row & 1023, oh = o >> 5, ow = o & 31;
#pragma unroll
    for (int tap = 0; tap < 4; ++tap) {
      int n = ((oh << 1) + (tap >> 1)) * 64 + (ow << 1) + (tap & 1);
      base[tap] = ((b << 12) + n) << 8;
    }
  }

  f32x4 acc[2][2];
#pragma unroll
  for (int mt = 0; mt < 2; ++mt)
#pragma unroll
    for (int nt = 0; nt < 2; ++nt)
#pragma unroll
      for (int r = 0; r < 4; ++r) acc[mt][nt][r] = 0.f;

  for (int k0 = 0; k0 < 1024; k0 += 32) {
    const int tap = k0 >> 8, ci0 = (k0 & 255) + sh * 8;
    __syncthreads();
    u16x8 av = *reinterpret_cast<const u16x8*>(&Xb[base[tap] + ci0]);
    *reinterpret_cast<u16x8*>(&Asb[sr * 40 + sh * 8]) = av;
    u16x8 wv = *reinterpret_cast<const u16x8*>(
        &Wp[(size_t)(n0 + sr) * 1024 + k0 + sh * 8]);
    *reinterpret_cast<u16x8*>(&Bsb[sr * 40 + sh * 8]) = wv;
    __syncthreads();
    bf16x8 af[2], bfr[2];
#pragma unroll
    for (int mt = 0; mt < 2; ++mt)
      af[mt] = *reinterpret_cast<const bf16x8*>(
          &Asb[(wr * 32 + mt * 16 + c) * 40 + g * 8]);
#pragma unroll
    for (int nt = 0; nt < 2; ++nt)
      bfr[nt] = *reinterpret_cast<const bf16x8*>(
          &Bsb[(wc * 32 + nt * 16 + c) * 40 + g * 8]);
#pragma unroll
    for (int mt = 0; mt < 2; ++mt)
#pragma unroll
      for (int nt = 0; nt < 2; ++nt)
        acc[mt][nt] = __builtin_amdgcn_mfma_f32_16x16x32_bf16(
            af[mt], bfr[nt], acc[mt][nt], 0, 0, 0);
  }

#pragma unroll
  for (int mt = 0; mt < 2; ++mt)
#pragma unroll
    for (int nt = 0; nt < 2; ++nt) {
      int row = m0 + wr * 32 + mt * 16 + g * 4;
      int col = n0 + wc * 32 + nt * 16 + c;
      float bv = bias[col];
#pragma unroll
      for (int r = 0; r < 4; ++r)
        C[(size_t)(row + r) * 256 + col] = acc[mt][nt][r] + bv;
    }
}

// ---------------------------------------------------------------------------
// LayerNorm over C=256; f32 in, bf16 out.
__global__ __launch_bounds__(256) void ln_kernel(
    const float* __restrict__ xr, const float* __restrict__ gam,
    const float* __restrict__ bet, unsigned short* __restrict__ xo) {
  const int row = blockIdx.x;
  const int t = threadIdx.x;
  float v = xr[(size_t)row * 256 + t];
  float s = v, s2 = v * v;
#pragma unroll
  for (int off = 32; off > 0; off >>= 1) {
    s  += __shfl_down(s, off, 64);
    s2 += __shfl_down(s2, off, 64);
  }
  __shared__ float red[8];
  const int wid = t >> 6;
  if ((t & 63) == 0) { red[wid] = s; red[wid + 4] = s2; }
  __syncthreads();
  s  = red[0] + red[1] + red[2] + red[3];
  s2 = red[4] + red[5] + red[6] + red[7];
  float mean = s * (1.f / 256.f);
  float var = s2 * (1.f / 256.f) - mean * mean;
  float rstd = rsqrtf(var + 1e-5f);
  xo[(size_t)row * 256 + t] = f2bf((v - mean) * rstd * gam[t] + bet[t]);
}

// ---------------------------------------------------------------------------
// 32x32x16-MFMA flash attention, split-KV x2, no LDS in main loop.
// Block = 2 waves, 32 q rows; wave w does kv [w*512, w*512+512) (8 tiles).
// Q pre-scaled by (1/sqrt(d))*log2e; flat softmax (scores bounded).
// K from Kb [4096][256]; V^T from Vt [(b*8+h)*32+d][1024].
__global__ __launch_bounds__(128) void attn_mfma(
    const unsigned short* __restrict__ Qb,
    const unsigned short* __restrict__ Kb,
    const unsigned short* __restrict__ Vt,
    unsigned short* __restrict__ O) {
  __shared__ float Obuf[2][32][33];
  __shared__ float Lb[2][32];

  const int tid = threadIdx.x;
  const int w = tid >> 6, l = tid & 63;
  const int q32 = l & 31, hi = l >> 5;
  const int wg = blockIdx.x;
  const int qb = wg & 127, head = (wg >> 7) & 7, b = wg >> 10;
  const int hcol = head << 5;
  const int q0 = (b << 12) + (qb << 5);

  // Q B-frags (pre-scaled)
  bf16x8 qf[2];
  {
    const unsigned short* qp = Qb + (size_t)(q0 + q32) * 256 + hcol + hi * 8;
    qf[0] = *reinterpret_cast<const bf16x8*>(qp);
    qf[1] = *reinterpret_cast<const bf16x8*>(qp + 16);
  }

  const unsigned short* kbase0 =
      Kb + ((size_t)(b << 10) + (w << 9) + q32) * 256 + hcol + hi * 8;
  const unsigned short* vrow =
      Vt + ((size_t)((b << 3) + head) * 32 + q32) * 1024 + (w << 9) + hi * 8;

  f32x16 acc;
#pragma unroll
  for (int r = 0; r < 16; ++r) acc[r] = 0.f;
  float lsum = 0.f;

  for (int t = 0; t < 8; ++t) {
    // ---- QK^T (swapped): S^T[kv][q] = mfma32(K, Q) ----
    const unsigned short* kbase = kbase0 + (size_t)t * 64 * 256;
    f32x16 s[2];
    {
      bf16x8 k00 = *reinterpret_cast<const bf16x8*>(kbase);
      bf16x8 k01 = *reinterpret_cast<const bf16x8*>(kbase + 16);
      bf16x8 k10 = *reinterpret_cast<const bf16x8*>(kbase + 32 * 256);
      bf16x8 k11 = *reinterpret_cast<const bf16x8*>(kbase + 32 * 256 + 16);
      f32x16 z;
#pragma unroll
      for (int r = 0; r < 16; ++r) z[r] = 0.f;
      s[0] = __builtin_amdgcn_mfma_f32_32x32x16_bf16(k00, qf[0], z, 0, 0, 0);
      s[0] = __builtin_amdgcn_mfma_f32_32x32x16_bf16(k01, qf[1], s[0], 0, 0, 0);
      s[1] = __builtin_amdgcn_mfma_f32_32x32x16_bf16(k10, qf[0], z, 0, 0, 0);
      s[1] = __builtin_amdgcn_mfma_f32_32x32x16_bf16(k11, qf[1], s[1], 0, 0, 0);
    }

    // ---- softmax + in-register P redistribution + PV ----
#pragma unroll
    for (int kvb = 0; kvb < 2; ++kvb) {
      float p[16];
#pragma unroll
      for (int r = 0; r < 16; ++r) {
        p[r] = __builtin_amdgcn_exp2f(s[kvb][r]);
        lsum += p[r];
      }
      unsigned A[8];
#pragma unroll
      for (int i = 0; i < 8; ++i) {
        unsigned o;
        asm("v_cvt_pk_bf16_f32 %0, %1, %2"
            : "=v"(o) : "v"(p[2 * i]), "v"(p[2 * i + 1]));
        A[i] = o;
      }
      u32x2v r02 = __builtin_amdgcn_permlane32_swap(A[0], A[2], false, false);
      u32x2v r13 = __builtin_amdgcn_permlane32_swap(A[1], A[3], false, false);
      u32x2v r46 = __builtin_amdgcn_permlane32_swap(A[4], A[6], false, false);
      u32x2v r57 = __builtin_amdgcn_permlane32_swap(A[5], A[7], false, false);
      u32x4v pk0 = {r02[0], r13[0], r02[1], r13[1]};
      u32x4v pk1 = {r46[0], r57[0], r46[1], r57[1]};
      bf16x8 pf0 = __builtin_bit_cast(bf16x8, pk0);
      bf16x8 pf1 = __builtin_bit_cast(bf16x8, pk1);
      const unsigned short* vp = vrow + t * 64 + kvb * 32;
      bf16x8 vf0 = *reinterpret_cast<const bf16x8*>(vp);
      bf16x8 vf1 = *reinterpret_cast<const bf16x8*>(vp + 16);
      acc = __builtin_amdgcn_mfma_f32_32x32x16_bf16(vf0, pf0, acc, 0, 0, 0);
      acc = __builtin_amdgcn_mfma_f32_32x32x16_bf16(vf1, pf1, acc, 0, 0, 0);
    }
  }

  // ---- merge the two KV halves via LDS ----
  lsum += __shfl_xor(lsum, 32, 64);
#pragma unroll
  for (int r = 0; r < 16; ++r)
    Obuf[w][q32][(r & 3) + 8 * (r >> 2) + 4 * hi] = acc[r];
  if (l < 32) Lb[w][l] = lsum;
  __syncthreads();

  const int q = tid >> 2, d0 = (tid & 3) << 3;
  float inv = 1.f / (Lb[0][q] + Lb[1][q]);
  unsigned wd[4];
#pragma unroll
  for (int j = 0; j < 4; ++j) {
    float o0 = (Obuf[0][q][d0 + 2 * j] + Obuf[1][q][d0 + 2 * j]) * inv;
    float o1 = (Obuf[0][q][d0 + 2 * j + 1] + Obuf[1][q][d0 + 2 * j + 1]) * inv;
    asm("v_cvt_pk_bf16_f32 %0, %1, %2" : "=v"(wd[j]) : "v"(o0), "v"(o1));
  }
  u32x4v pk = {wd[0], wd[1], wd[2], wd[3]};
  *reinterpret_cast<u32x4v*>(&O[(size_t)(q0 + q) * 256 + hcol + d0]) = pk;
}

// ---------------------------------------------------------------------------
extern "C" void kernel_launch(void* const* d_in, const int* in_sizes, int n_in,
                              void* d_out, int out_size, void* d_ws,
                              size_t ws_size, hipStream_t stream) {
  const float* x      = (const float*)d_in[0];
  const float* sr_w   = (const float*)d_in[3];
  const float* sr_b   = (const float*)d_in[4];
  const float* ln_g   = (const float*)d_in[5];
  const float* ln_b   = (const float*)d_in[6];
  const float* q_w    = (const float*)d_in[7];
  const float* kv_w   = (const float*)d_in[8];
  const float* proj_w = (const float*)d_in[9];
  const float* proj_b = (const float*)d_in[10];
  float* out = (float*)d_out;

  char* ws = (char*)d_ws;
  unsigned short* x_bf    = (unsigned short*)(ws);               // 8 MB
  unsigned short* q_bf    = (unsigned short*)(ws + 8388608);     // 8 MB
  unsigned short* srw_bf  = (unsigned short*)(ws + 16777216);    // 512 KB
  float*          xred    = (float*)(ws + 17301504);             // 4 MB
  unsigned short* x_ln    = (unsigned short*)(ws + 21495808);    // 2 MB
  unsigned short* k_buf   = (unsigned short*)(ws + 23592960);    // 2 MB
  unsigned short* vt_buf  = (unsigned short*)(ws + 25690112);    // 2 MB
  unsigned short* attn_bf = (unsigned short*)(ws + 27787264);    // 8 MB

  const float qscale = 0.25506975154985854f;  // (1/sqrt(32)) * log2(e)

  // 0. casts / weight permute
  cast_bf16<<<2048, 256, 0, stream>>>(x, x_bf, 524288);
  perm_srw<<<256, 256, 0, stream>>>(sr_w, srw_bf);
  // 1. q = (x @ q_w^T) * qscale (bf16)
  mfma_gemm<true, false, false><<<dim3(4, 128), 256, 0, stream>>>(
      x_bf, q_w, nullptr, q_bf, nullptr, 16384, 256, 256, qscale);
  // 2. conv(k=2,s=2) + bias (f32)
  conv_mfma<<<dim3(4, 64), 256, 0, stream>>>(x_bf, srw_bf, sr_b, xred);
  // 3. LayerNorm (bf16 out)
  ln_kernel<<<4096, 256, 0, stream>>>(xred, ln_g, ln_b, x_ln);
  // 4. kv = x_ln @ kv_w^T -> K row-major + V transposed
  mfma_gemm<true, false, true><<<dim3(8, 32), 256, 0, stream>>>(
      x_ln, kv_w, nullptr, k_buf, vt_buf, 4096, 512, 256, 1.0f);
  // 5. attention (bf16 out), split-KV x2
  attn_mfma<<<4096, 128, 0, stream>>>(q_bf, k_buf, vt_buf, attn_bf);
  // 6. out = attn_o @ proj_w^T + proj_b (f32)
  mfma_gemm<false, true, false><<<dim3(4, 128), 256, 0, stream>>>(
      attn_bf, proj_w, proj_b, out, nullptr, 16384, 256, 256, 1.0f);
}